// Round 1
// 1340.939 us; speedup vs baseline: 1.2522x; 1.2522x over previous
//
#include <hip/hip_runtime.h>

// ALIGNNMT gated-GCN layer, MI355X/gfx950. Round 4.
// Theory: k_edge was issue/L1-bound re-streaming Weg (16KB) per edge.
// Fix: column c = tid&63 is invariant under grid-stride (stride % 64 == 0),
// so hoist the weight column into 64 VGPRs once per thread; ef row read as
// 16 lane-uniform float4s. fp32 atomics via unsafeAtomicAdd (HW
// global_atomic_add_f32, fire-and-forget, no CAS loop). Node linears split
// into 2 kernels x 2 matrices (128 hoisted VGPRs each). Epilogues float4.

__device__ __forceinline__ float sigm(float x) {
    return 1.0f / (1.0f + __expf(-x));
}

// ---------------- K1a/K1b: node linears, 2 weight matrices per kernel ----------------
// Each thread owns column c = tid&63 forever; hoists W0[:,c], W1[:,c] into regs.
__global__ __launch_bounds__(256) void k_node_lin2(
    const float* __restrict__ nf,
    const float* __restrict__ W0, const float* __restrict__ b0,
    const float* __restrict__ W1, const float* __restrict__ b1,
    float* __restrict__ o0, float* __restrict__ o1, int N)
{
    int tid = threadIdx.x;
    int c = tid & 63;
    float w0[64], w1[64];
    #pragma unroll
    for (int k = 0; k < 64; k++) {
        w0[k] = W0[k * 64 + c];
        w1[k] = W1[k * 64 + c];
    }
    float bb0 = b0[c], bb1 = b1[c];
    int stride = gridDim.x * 256;              // multiple of 64 -> c invariant
    for (int i = blockIdx.x * 256 + tid; i < N * 64; i += stride) {
        int n = i >> 6;
        const float4* a4 = (const float4*)(nf + ((size_t)n << 6));
        float s0a = bb0, s0b = 0.f, s1a = bb1, s1b = 0.f;
        #pragma unroll
        for (int k = 0; k < 16; k++) {
            float4 v = a4[k];                  // lane-uniform, 1 txn/wave
            s0a = fmaf(v.x, w0[4 * k + 0], s0a);
            s0b = fmaf(v.y, w0[4 * k + 1], s0b);
            s0a = fmaf(v.z, w0[4 * k + 2], s0a);
            s0b = fmaf(v.w, w0[4 * k + 3], s0b);
            s1a = fmaf(v.x, w1[4 * k + 0], s1a);
            s1b = fmaf(v.y, w1[4 * k + 1], s1b);
            s1a = fmaf(v.z, w1[4 * k + 2], s1a);
            s1b = fmaf(v.w, w1[4 * k + 3], s1b);
        }
        o0[i] = s0a + s0b;
        o1[i] = s1a + s1b;
    }
}

// ---------------- K2: edge gate GEMM + gather + sigmoid + scatter + edge BN stats ----------------
__global__ __launch_bounds__(256) void k_edge(
    const float* __restrict__ ef, const int* __restrict__ src, const int* __restrict__ dst,
    const float* __restrict__ Weg, const float* __restrict__ beg,
    const float* __restrict__ esrc, const float* __restrict__ edst, const float* __restrict__ Bh,
    float* __restrict__ ssig, float* __restrict__ ssigh,
    float* __restrict__ mout, float* __restrict__ stat, int E)
{
    int tid = threadIdx.x;
    int c = tid & 63;
    float w[64];                               // Weg[:,c] hoisted: read ONCE per thread
    #pragma unroll
    for (int k = 0; k < 64; k++) w[k] = Weg[k * 64 + c];
    float bc = beg[c];

    int stride = gridDim.x * 256;              // multiple of 64 -> c invariant
    float sts = 0.f, stq = 0.f;
    for (int i = blockIdx.x * 256 + tid; i < E * 64; i += stride) {
        int e = i >> 6;
        int sN = src[e], dN = dst[e];          // lane-uniform
        const float4* a4 = (const float4*)(ef + ((size_t)e << 6));
        float m0 = bc, m1 = 0.f, m2 = 0.f, m3 = 0.f;
        #pragma unroll
        for (int k = 0; k < 16; k++) {
            float4 v = a4[k];                  // lane-uniform, 1 txn/wave
            m0 = fmaf(v.x, w[4 * k + 0], m0);
            m1 = fmaf(v.y, w[4 * k + 1], m1);
            m2 = fmaf(v.z, w[4 * k + 2], m2);
            m3 = fmaf(v.w, w[4 * k + 3], m3);
        }
        float m = (m0 + m1) + (m2 + m3);
        m += esrc[((size_t)sN << 6) + c] + edst[((size_t)dN << 6) + c];
        mout[i] = m;
        sts += m; stq += m * m;
        float sg = sigm(m);
        unsafeAtomicAdd(&ssig[((size_t)dN << 6) + c], sg);
        unsafeAtomicAdd(&ssigh[((size_t)dN << 6) + c], sg * Bh[((size_t)sN << 6) + c]);
    }
    // block reduction: threads tid, tid+64, tid+128, tid+192 share column tid&63
    __shared__ float r1[256], r2[256];
    r1[tid] = sts; r2[tid] = stq;
    __syncthreads();
    if (tid < 64) {
        float a = r1[tid] + r1[tid + 64] + r1[tid + 128] + r1[tid + 192];
        float b = r2[tid] + r2[tid + 64] + r2[tid + 128] + r2[tid + 192];
        unsafeAtomicAdd(&stat[tid], a);
        unsafeAtomicAdd(&stat[64 + tid], b);
    }
}

// ---------------- K3: h = ssigh/(ssig+1e-6), x_pre = xs + h, node BN stats ----------------
__global__ __launch_bounds__(256) void k_node_agg(
    const float* __restrict__ ssig, const float* __restrict__ ssigh,
    const float* __restrict__ xs, float* __restrict__ xpre,
    float* __restrict__ stat, int N)
{
    int tid = threadIdx.x;
    int stride = gridDim.x * 256;
    float sts = 0.f, stq = 0.f;
    for (int i = blockIdx.x * 256 + tid; i < N * 64; i += stride) {
        float a = ssig[i];
        float xv = xs[i] + ssigh[i] / (fmaxf(a, 0.f) + 1e-6f);
        xpre[i] = xv;
        sts += xv; stq += xv * xv;
    }
    __shared__ float r1[256], r2[256];
    r1[tid] = sts; r2[tid] = stq;
    __syncthreads();
    if (tid < 64) {
        float a = r1[tid] + r1[tid + 64] + r1[tid + 128] + r1[tid + 192];
        float b = r2[tid] + r2[tid + 64] + r2[tid + 128] + r2[tid + 192];
        unsafeAtomicAdd(&stat[128 + tid], a);
        unsafeAtomicAdd(&stat[192 + tid], b);
    }
}

// ---------------- K4: finalize BN scale/shift ----------------
__global__ __launch_bounds__(128) void k_finalize(
    const float* __restrict__ stat,
    const float* __restrict__ gn, const float* __restrict__ bn,
    const float* __restrict__ ge, const float* __restrict__ be,
    float* __restrict__ scsh, int N, int E)
{
    int t = threadIdx.x;
    if (t < 64) {
        float inv = 1.0f / (float)E;
        float mean = stat[t] * inv;
        float var = fmaxf(stat[64 + t] * inv - mean * mean, 0.0f);
        float rs = rsqrtf(var + 1e-5f);
        float g = ge[t], b = be[t];
        scsh[t] = g * rs;                   // edge scale
        scsh[64 + t] = b - mean * g * rs;   // edge shift
    } else {
        int c = t - 64;
        float inv = 1.0f / (float)N;
        float mean = stat[128 + c] * inv;
        float var = fmaxf(stat[192 + c] * inv - mean * mean, 0.0f);
        float rs = rsqrtf(var + 1e-5f);
        float g = gn[c], b = bn[c];
        scsh[128 + c] = g * rs;             // node scale
        scsh[192 + c] = b - mean * g * rs;  // node shift
    }
}

// ---------------- K5: x_out = nf + silu(bn(x_pre)), float4 ----------------
__global__ __launch_bounds__(256) void k_node_out(
    const float* __restrict__ nf, const float* __restrict__ xpre,
    const float* __restrict__ scsh, float* __restrict__ out, int N)
{
    int i = blockIdx.x * 256 + threadIdx.x;    // over N*16 float4s
    if (i >= N * 16) return;
    int c4 = (i & 15) << 2;
    float4 xv = ((const float4*)xpre)[i];
    float4 nv = ((const float4*)nf)[i];
    float4 r;
    {
        float v = xv.x * scsh[128 + c4 + 0] + scsh[192 + c4 + 0]; r.x = nv.x + v * sigm(v);
    }
    {
        float v = xv.y * scsh[128 + c4 + 1] + scsh[192 + c4 + 1]; r.y = nv.y + v * sigm(v);
    }
    {
        float v = xv.z * scsh[128 + c4 + 2] + scsh[192 + c4 + 2]; r.z = nv.z + v * sigm(v);
    }
    {
        float v = xv.w * scsh[128 + c4 + 3] + scsh[192 + c4 + 3]; r.w = nv.w + v * sigm(v);
    }
    ((float4*)out)[i] = r;
}

// ---------------- K6: y_out = ef + silu(bn(m)), in place on outy, float4 ----------------
__global__ __launch_bounds__(256) void k_edge_out(
    const float* __restrict__ ef, const float* __restrict__ scsh,
    float* __restrict__ outy, int E)
{
    int i = blockIdx.x * 256 + threadIdx.x;    // over E*16 float4s
    if (i >= E * 16) return;
    int c4 = (i & 15) << 2;
    float4 mv = ((const float4*)outy)[i];
    float4 ev = ((const float4*)ef)[i];
    float4 r;
    {
        float v = mv.x * scsh[c4 + 0] + scsh[64 + c4 + 0]; r.x = ev.x + v * sigm(v);
    }
    {
        float v = mv.y * scsh[c4 + 1] + scsh[64 + c4 + 1]; r.y = ev.y + v * sigm(v);
    }
    {
        float v = mv.z * scsh[c4 + 2] + scsh[64 + c4 + 2]; r.z = ev.z + v * sigm(v);
    }
    {
        float v = mv.w * scsh[c4 + 3] + scsh[64 + c4 + 3]; r.w = ev.w + v * sigm(v);
    }
    ((float4*)outy)[i] = r;
}

extern "C" void kernel_launch(void* const* d_in, const int* in_sizes, int n_in,
                              void* d_out, int out_size, void* d_ws, size_t ws_size,
                              hipStream_t stream)
{
    const float* nf  = (const float*)d_in[0];
    const float* ef  = (const float*)d_in[1];
    const int*   src = (const int*)d_in[2];
    const int*   dst = (const int*)d_in[3];
    const float* Wsg = (const float*)d_in[4];
    const float* bsg = (const float*)d_in[5];
    const float* Wdg = (const float*)d_in[6];
    const float* bdg = (const float*)d_in[7];
    const float* Weg = (const float*)d_in[8];
    const float* beg = (const float*)d_in[9];
    const float* Wsu = (const float*)d_in[10];
    const float* bsu = (const float*)d_in[11];
    const float* Wdu = (const float*)d_in[12];
    const float* bdu = (const float*)d_in[13];
    const float* gn  = (const float*)d_in[14];
    const float* bn  = (const float*)d_in[15];
    const float* ge  = (const float*)d_in[16];
    const float* be  = (const float*)d_in[17];

    int N = in_sizes[0] / 64;
    int E = in_sizes[2];

    char* ws = (char*)d_ws;
    size_t NF = (size_t)N * 64 * 4;   // one [N,64] fp32 array, bytes
    // layout: [esrc][edst][Bh][xs][ssig][ssigh][stat 1KB][scsh 1KB][xpre]
    size_t need = 7 * NF + 2048;
    if (ws_size < need) return;

    float* esrc = (float*)(ws);
    float* edst = (float*)(ws + NF);
    float* Bh   = (float*)(ws + 2 * NF);
    float* xs   = (float*)(ws + 3 * NF);
    float* ssig = (float*)(ws + 4 * NF);
    float* ssigh= (float*)(ws + 5 * NF);
    float* stat = (float*)(ws + 6 * NF);          // 256 floats
    float* scsh = (float*)(ws + 6 * NF + 1024);   // 256 floats
    float* xpre = (float*)(ws + 6 * NF + 2048);

    float* outx = (float*)d_out;
    float* outy = outx + (size_t)N * 64;   // m staged here, finalized in place by K6

    // zero: ssig, ssigh, stat
    hipMemsetAsync(ws + 4 * NF, 0, 2 * NF + 1024, stream);

    hipLaunchKernelGGL(k_node_lin2, dim3(1024), dim3(256), 0, stream,
                       nf, Wsg, bsg, Wdg, bdg, esrc, edst, N);
    hipLaunchKernelGGL(k_node_lin2, dim3(1024), dim3(256), 0, stream,
                       nf, Wdu, bdu, Wsu, bsu, Bh, xs, N);
    hipLaunchKernelGGL(k_edge, dim3(2048), dim3(256), 0, stream,
                       ef, src, dst, Weg, beg, esrc, edst, Bh,
                       ssig, ssigh, outy, stat, E);
    hipLaunchKernelGGL(k_node_agg, dim3(1024), dim3(256), 0, stream,
                       ssig, ssigh, xs, xpre, stat, N);
    hipLaunchKernelGGL(k_finalize, dim3(1), dim3(128), 0, stream,
                       stat, gn, bn, ge, be, scsh, N, E);
    hipLaunchKernelGGL(k_node_out, dim3((N * 16 + 255) / 256), dim3(256), 0, stream,
                       nf, xpre, scsh, outx, N);
    hipLaunchKernelGGL(k_edge_out, dim3((E * 16 + 255) / 256), dim3(256), 0, stream,
                       ef, scsh, outy, E);
}

// Round 2
// 1326.022 us; speedup vs baseline: 1.2663x; 1.0112x over previous
//
#include <hip/hip_runtime.h>

// ALIGNNMT gated-GCN layer, MI355X/gfx950. Round 5.
// Theory: k_edge latency-bound (VALU 13%, HBM 16%, occ 47%) — one serial
// dependency chain (src/dst -> gathers -> atomics) per wave-iteration.
// Fix: 2-edge unroll (two independent chains in flight) + readfirstlane
// scalarization of wave-uniform src/dst loads and gather bases (s_load +
// saddr-form global_load). ef row loads stay vector float4 broadcasts so
// they sit on VMEM with deep vmcnt (64 SGPRs wouldn't fit the SGPR file).

__device__ __forceinline__ float sigm(float x) {
    return 1.0f / (1.0f + __expf(-x));
}

// ---------------- K1a/K1b: node linears, 2 weight matrices per kernel ----------------
__global__ __launch_bounds__(256) void k_node_lin2(
    const float* __restrict__ nf,
    const float* __restrict__ W0, const float* __restrict__ b0,
    const float* __restrict__ W1, const float* __restrict__ b1,
    float* __restrict__ o0, float* __restrict__ o1, int N)
{
    int tid = threadIdx.x;
    int c = tid & 63;
    float w0[64], w1[64];
    #pragma unroll
    for (int k = 0; k < 64; k++) {
        w0[k] = W0[k * 64 + c];
        w1[k] = W1[k * 64 + c];
    }
    float bb0 = b0[c], bb1 = b1[c];
    int stride = gridDim.x * 256;              // multiple of 64 -> c invariant
    for (int i = blockIdx.x * 256 + tid; i < N * 64; i += stride) {
        int n = i >> 6;
        const float4* a4 = (const float4*)(nf + ((size_t)n << 6));
        float s0a = bb0, s0b = 0.f, s1a = bb1, s1b = 0.f;
        #pragma unroll
        for (int k = 0; k < 16; k++) {
            float4 v = a4[k];                  // lane-uniform, 1 txn/wave
            s0a = fmaf(v.x, w0[4 * k + 0], s0a);
            s0b = fmaf(v.y, w0[4 * k + 1], s0b);
            s0a = fmaf(v.z, w0[4 * k + 2], s0a);
            s0b = fmaf(v.w, w0[4 * k + 3], s0b);
            s1a = fmaf(v.x, w1[4 * k + 0], s1a);
            s1b = fmaf(v.y, w1[4 * k + 1], s1b);
            s1a = fmaf(v.z, w1[4 * k + 2], s1a);
            s1b = fmaf(v.w, w1[4 * k + 3], s1b);
        }
        o0[i] = s0a + s0b;
        o1[i] = s1a + s1b;
    }
}

// ---------------- K2: edge gate GEMM + gather + sigmoid + scatter + edge BN stats ----------------
__global__ __launch_bounds__(256) void k_edge(
    const float* __restrict__ ef, const int* __restrict__ src, const int* __restrict__ dst,
    const float* __restrict__ Weg, const float* __restrict__ beg,
    const float* __restrict__ esrc, const float* __restrict__ edst, const float* __restrict__ Bh,
    float* __restrict__ ssig, float* __restrict__ ssigh,
    float* __restrict__ mout, float* __restrict__ stat, int E)
{
    int tid = threadIdx.x;
    int c = tid & 63;
    float w[64];                               // Weg[:,c] per-thread
    #pragma unroll
    for (int k = 0; k < 64; k++) w[k] = Weg[k * 64 + c];
    float bc = beg[c];

    int total = E * 64;
    int stride = gridDim.x * 256;              // multiple of 64 -> c invariant
    float sts = 0.f, stq = 0.f;
    int i = blockIdx.x * 256 + tid;

    // main loop: two independent edge rows in flight per iteration
    for (; i + stride < total; i += 2 * stride) {
        int i0 = i, i1 = i + stride;
        int ev0 = i0 >> 6, ev1 = i1 >> 6;      // wave-uniform (vector form for ef ptr)
        int e0 = __builtin_amdgcn_readfirstlane(ev0);
        int e1 = __builtin_amdgcn_readfirstlane(ev1);
        int sN0 = src[e0], dN0 = dst[e0];      // s_load_dword
        int sN1 = src[e1], dN1 = dst[e1];
        const float4* a40 = (const float4*)(ef + ((size_t)ev0 << 6));
        const float4* a41 = (const float4*)(ef + ((size_t)ev1 << 6));
        // issue both rows' gathers up front (independent chains)
        float es0 = esrc[((size_t)sN0 << 6) + c];
        float ed0 = edst[((size_t)dN0 << 6) + c];
        float bh0 = Bh  [((size_t)sN0 << 6) + c];
        float es1 = esrc[((size_t)sN1 << 6) + c];
        float ed1 = edst[((size_t)dN1 << 6) + c];
        float bh1 = Bh  [((size_t)sN1 << 6) + c];
        float p0 = bc, p1 = 0.f, p2 = 0.f, p3 = 0.f;
        float q0 = bc, q1 = 0.f, q2 = 0.f, q3 = 0.f;
        #pragma unroll
        for (int k = 0; k < 16; k++) {
            float4 v0 = a40[k];                // lane-uniform broadcast, VMEM
            float4 v1 = a41[k];
            p0 = fmaf(v0.x, w[4 * k + 0], p0);
            p1 = fmaf(v0.y, w[4 * k + 1], p1);
            p2 = fmaf(v0.z, w[4 * k + 2], p2);
            p3 = fmaf(v0.w, w[4 * k + 3], p3);
            q0 = fmaf(v1.x, w[4 * k + 0], q0);
            q1 = fmaf(v1.y, w[4 * k + 1], q1);
            q2 = fmaf(v1.z, w[4 * k + 2], q2);
            q3 = fmaf(v1.w, w[4 * k + 3], q3);
        }
        float m0 = (p0 + p1) + (p2 + p3) + es0 + ed0;
        float m1 = (q0 + q1) + (q2 + q3) + es1 + ed1;
        mout[i0] = m0;
        mout[i1] = m1;
        sts += m0 + m1;
        stq += m0 * m0 + m1 * m1;
        float sg0 = sigm(m0), sg1 = sigm(m1);
        unsafeAtomicAdd(&ssig [((size_t)dN0 << 6) + c], sg0);
        unsafeAtomicAdd(&ssigh[((size_t)dN0 << 6) + c], sg0 * bh0);
        unsafeAtomicAdd(&ssig [((size_t)dN1 << 6) + c], sg1);
        unsafeAtomicAdd(&ssigh[((size_t)dN1 << 6) + c], sg1 * bh1);
    }
    // tail: at most one row left per thread
    if (i < total) {
        int ev0 = i >> 6;
        int e0 = __builtin_amdgcn_readfirstlane(ev0);
        int sN0 = src[e0], dN0 = dst[e0];
        const float4* a40 = (const float4*)(ef + ((size_t)ev0 << 6));
        float es0 = esrc[((size_t)sN0 << 6) + c];
        float ed0 = edst[((size_t)dN0 << 6) + c];
        float bh0 = Bh  [((size_t)sN0 << 6) + c];
        float p0 = bc, p1 = 0.f, p2 = 0.f, p3 = 0.f;
        #pragma unroll
        for (int k = 0; k < 16; k++) {
            float4 v0 = a40[k];
            p0 = fmaf(v0.x, w[4 * k + 0], p0);
            p1 = fmaf(v0.y, w[4 * k + 1], p1);
            p2 = fmaf(v0.z, w[4 * k + 2], p2);
            p3 = fmaf(v0.w, w[4 * k + 3], p3);
        }
        float m0 = (p0 + p1) + (p2 + p3) + es0 + ed0;
        mout[i] = m0;
        sts += m0;
        stq += m0 * m0;
        float sg0 = sigm(m0);
        unsafeAtomicAdd(&ssig [((size_t)dN0 << 6) + c], sg0);
        unsafeAtomicAdd(&ssigh[((size_t)dN0 << 6) + c], sg0 * bh0);
    }

    // block reduction: threads tid, tid+64, tid+128, tid+192 share column tid&63
    __shared__ float r1[256], r2[256];
    r1[tid] = sts; r2[tid] = stq;
    __syncthreads();
    if (tid < 64) {
        float a = r1[tid] + r1[tid + 64] + r1[tid + 128] + r1[tid + 192];
        float b = r2[tid] + r2[tid + 64] + r2[tid + 128] + r2[tid + 192];
        unsafeAtomicAdd(&stat[tid], a);
        unsafeAtomicAdd(&stat[64 + tid], b);
    }
}

// ---------------- K3: h = ssigh/(ssig+1e-6), x_pre = xs + h, node BN stats ----------------
__global__ __launch_bounds__(256) void k_node_agg(
    const float* __restrict__ ssig, const float* __restrict__ ssigh,
    const float* __restrict__ xs, float* __restrict__ xpre,
    float* __restrict__ stat, int N)
{
    int tid = threadIdx.x;
    int stride = gridDim.x * 256;
    float sts = 0.f, stq = 0.f;
    for (int i = blockIdx.x * 256 + tid; i < N * 64; i += stride) {
        float a = ssig[i];
        float xv = xs[i] + ssigh[i] / (fmaxf(a, 0.f) + 1e-6f);
        xpre[i] = xv;
        sts += xv; stq += xv * xv;
    }
    __shared__ float r1[256], r2[256];
    r1[tid] = sts; r2[tid] = stq;
    __syncthreads();
    if (tid < 64) {
        float a = r1[tid] + r1[tid + 64] + r1[tid + 128] + r1[tid + 192];
        float b = r2[tid] + r2[tid + 64] + r2[tid + 128] + r2[tid + 192];
        unsafeAtomicAdd(&stat[128 + tid], a);
        unsafeAtomicAdd(&stat[192 + tid], b);
    }
}

// ---------------- K4: finalize BN scale/shift ----------------
__global__ __launch_bounds__(128) void k_finalize(
    const float* __restrict__ stat,
    const float* __restrict__ gn, const float* __restrict__ bn,
    const float* __restrict__ ge, const float* __restrict__ be,
    float* __restrict__ scsh, int N, int E)
{
    int t = threadIdx.x;
    if (t < 64) {
        float inv = 1.0f / (float)E;
        float mean = stat[t] * inv;
        float var = fmaxf(stat[64 + t] * inv - mean * mean, 0.0f);
        float rs = rsqrtf(var + 1e-5f);
        float g = ge[t], b = be[t];
        scsh[t] = g * rs;                   // edge scale
        scsh[64 + t] = b - mean * g * rs;   // edge shift
    } else {
        int c = t - 64;
        float inv = 1.0f / (float)N;
        float mean = stat[128 + c] * inv;
        float var = fmaxf(stat[192 + c] * inv - mean * mean, 0.0f);
        float rs = rsqrtf(var + 1e-5f);
        float g = gn[c], b = bn[c];
        scsh[128 + c] = g * rs;             // node scale
        scsh[192 + c] = b - mean * g * rs;  // node shift
    }
}

// ---------------- K5: x_out = nf + silu(bn(x_pre)), float4 ----------------
__global__ __launch_bounds__(256) void k_node_out(
    const float* __restrict__ nf, const float* __restrict__ xpre,
    const float* __restrict__ scsh, float* __restrict__ out, int N)
{
    int i = blockIdx.x * 256 + threadIdx.x;    // over N*16 float4s
    if (i >= N * 16) return;
    int c4 = (i & 15) << 2;
    float4 xv = ((const float4*)xpre)[i];
    float4 nv = ((const float4*)nf)[i];
    float4 r;
    { float v = xv.x * scsh[128 + c4 + 0] + scsh[192 + c4 + 0]; r.x = nv.x + v * sigm(v); }
    { float v = xv.y * scsh[128 + c4 + 1] + scsh[192 + c4 + 1]; r.y = nv.y + v * sigm(v); }
    { float v = xv.z * scsh[128 + c4 + 2] + scsh[192 + c4 + 2]; r.z = nv.z + v * sigm(v); }
    { float v = xv.w * scsh[128 + c4 + 3] + scsh[192 + c4 + 3]; r.w = nv.w + v * sigm(v); }
    ((float4*)out)[i] = r;
}

// ---------------- K6: y_out = ef + silu(bn(m)), in place on outy, float4 ----------------
__global__ __launch_bounds__(256) void k_edge_out(
    const float* __restrict__ ef, const float* __restrict__ scsh,
    float* __restrict__ outy, int E)
{
    int i = blockIdx.x * 256 + threadIdx.x;    // over E*16 float4s
    if (i >= E * 16) return;
    int c4 = (i & 15) << 2;
    float4 mv = ((const float4*)outy)[i];
    float4 ev = ((const float4*)ef)[i];
    float4 r;
    { float v = mv.x * scsh[c4 + 0] + scsh[64 + c4 + 0]; r.x = ev.x + v * sigm(v); }
    { float v = mv.y * scsh[c4 + 1] + scsh[64 + c4 + 1]; r.y = ev.y + v * sigm(v); }
    { float v = mv.z * scsh[c4 + 2] + scsh[64 + c4 + 2]; r.z = ev.z + v * sigm(v); }
    { float v = mv.w * scsh[c4 + 3] + scsh[64 + c4 + 3]; r.w = ev.w + v * sigm(v); }
    ((float4*)outy)[i] = r;
}

extern "C" void kernel_launch(void* const* d_in, const int* in_sizes, int n_in,
                              void* d_out, int out_size, void* d_ws, size_t ws_size,
                              hipStream_t stream)
{
    const float* nf  = (const float*)d_in[0];
    const float* ef  = (const float*)d_in[1];
    const int*   src = (const int*)d_in[2];
    const int*   dst = (const int*)d_in[3];
    const float* Wsg = (const float*)d_in[4];
    const float* bsg = (const float*)d_in[5];
    const float* Wdg = (const float*)d_in[6];
    const float* bdg = (const float*)d_in[7];
    const float* Weg = (const float*)d_in[8];
    const float* beg = (const float*)d_in[9];
    const float* Wsu = (const float*)d_in[10];
    const float* bsu = (const float*)d_in[11];
    const float* Wdu = (const float*)d_in[12];
    const float* bdu = (const float*)d_in[13];
    const float* gn  = (const float*)d_in[14];
    const float* bn  = (const float*)d_in[15];
    const float* ge  = (const float*)d_in[16];
    const float* be  = (const float*)d_in[17];

    int N = in_sizes[0] / 64;
    int E = in_sizes[2];

    char* ws = (char*)d_ws;
    size_t NF = (size_t)N * 64 * 4;   // one [N,64] fp32 array, bytes
    // layout: [esrc][edst][Bh][xs][ssig][ssigh][stat 1KB][scsh 1KB][xpre]
    size_t need = 7 * NF + 2048;
    if (ws_size < need) return;

    float* esrc = (float*)(ws);
    float* edst = (float*)(ws + NF);
    float* Bh   = (float*)(ws + 2 * NF);
    float* xs   = (float*)(ws + 3 * NF);
    float* ssig = (float*)(ws + 4 * NF);
    float* ssigh= (float*)(ws + 5 * NF);
    float* stat = (float*)(ws + 6 * NF);          // 256 floats
    float* scsh = (float*)(ws + 6 * NF + 1024);   // 256 floats
    float* xpre = (float*)(ws + 6 * NF + 2048);

    float* outx = (float*)d_out;
    float* outy = outx + (size_t)N * 64;   // m staged here, finalized in place by K6

    // zero: ssig, ssigh, stat
    hipMemsetAsync(ws + 4 * NF, 0, 2 * NF + 1024, stream);

    hipLaunchKernelGGL(k_node_lin2, dim3(1024), dim3(256), 0, stream,
                       nf, Wsg, bsg, Wdg, bdg, esrc, edst, N);
    hipLaunchKernelGGL(k_node_lin2, dim3(1024), dim3(256), 0, stream,
                       nf, Wdu, bdu, Wsu, bsu, Bh, xs, N);
    hipLaunchKernelGGL(k_edge, dim3(2048), dim3(256), 0, stream,
                       ef, src, dst, Weg, beg, esrc, edst, Bh,
                       ssig, ssigh, outy, stat, E);
    hipLaunchKernelGGL(k_node_agg, dim3(1024), dim3(256), 0, stream,
                       ssig, ssigh, xs, xpre, stat, N);
    hipLaunchKernelGGL(k_finalize, dim3(1), dim3(128), 0, stream,
                       stat, gn, bn, ge, be, scsh, N, E);
    hipLaunchKernelGGL(k_node_out, dim3((N * 16 + 255) / 256), dim3(256), 0, stream,
                       nf, xpre, scsh, outx, N);
    hipLaunchKernelGGL(k_edge_out, dim3((E * 16 + 255) / 256), dim3(256), 0, stream,
                       ef, scsh, outy, E);
}